// Round 7
// baseline (414.898 us; speedup 1.0000x reference)
//
#include <hip/hip_runtime.h>

#define LENF 15
#define BLK  5
#define NZ   1e-5f

typedef float f32x2 __attribute__((ext_vector_type(2)));

struct R3 { float p, t, e; };   // 12B record -> global_load_dwordx3

__device__ __forceinline__ f32x2 vmin2(f32x2 a, f32x2 b) {
  f32x2 r; r.x = fminf(a.x, b.x); r.y = fminf(a.y, b.y); return r;
}
__device__ __forceinline__ f32x2 vmax2(f32x2 a, f32x2 b) {
  f32x2 r; r.x = fmaxf(a.x, b.x); r.y = fmaxf(a.y, b.y); return r;
}

// Two cells packed into the .x / .y lanes of every register.
// Packed ops -> v_pk_{add,mul,fma}_f32: one instruction drives BOTH cells'
// dependency chains, so the scheduler cannot serialize them (R6 failure).
struct Pair {
  f32x2 ddf, Tbm, wrf, Tbf, Kf, exp_fe, ET_eff, c_run, c_v2p, c_vad, c_phr,
        vml, inv_vml;
  f32x2 sog, wis, vad, phr;
  f32x2 w1[LENF], w2[LENF];       // UH weights, cells-packed
  f32x2 s1[LENF - 1], s2[LENF - 1]; // transposed-FIR delay lines
};

__device__ __forceinline__ void descale_lane(const float* pp, float* d) {
  d[0]  = pp[0]  * 40.f;
  d[1]  = pp[1]  * 5.f  - 2.f;
  d[2]  = pp[2]  * 0.5f;
  d[3]  = pp[3]  * 7.f  - 5.f;
  d[4]  = pp[4]  * 5.f;
  d[5]  = pp[5];
  d[6]  = pp[6];
  d[7]  = pp[7];
  d[8]  = pp[8]  * (0.02f - 1e-5f) + 1e-5f;
  d[9]  = pp[9]  * 0.1f;
  d[10] = pp[10] * (0.01f - 1e-5f) + 1e-5f;
  d[11] = pp[11] * (500.f - 0.001f) + 0.001f;
  d[12] = 1.f / d[11];
}

// gamma UH weights; lgamma/theta terms cancel under normalization
__device__ __forceinline__ void uh_lane(float a, float b, float* w) {
  float lw[LENF], m = -1e30f;
  const float ib = 1.f / b;
#pragma unroll
  for (int l = 0; l < LENF; ++l) {
    float tt = l + 0.5f;
    lw[l] = (a - 1.f) * __logf(tt) - tt * ib;
    m = fmaxf(m, lw[l]);
  }
  float s = 0.f;
#pragma unroll
  for (int l = 0; l < LENF; ++l) { w[l] = __expf(lw[l] - m); s += w[l]; }
  const float r = 1.f / s;
#pragma unroll
  for (int l = 0; l < LENF; ++l) w[l] *= r;
}

__device__ __forceinline__ void init_pair(Pair& c, const float* ppx,
                                          const float* ppy) {
  float dx[13], dy[13];
  descale_lane(ppx, dx);
  descale_lane(ppy, dy);
  c.ddf     = (f32x2){dx[0],  dy[0]};
  c.Tbm     = (f32x2){dx[1],  dy[1]};
  c.wrf     = (f32x2){dx[2],  dy[2]};
  c.Tbf     = (f32x2){dx[3],  dy[3]};
  c.Kf      = (f32x2){dx[4],  dy[4]};
  c.exp_fe  = (f32x2){dx[5],  dy[5]};
  c.ET_eff  = (f32x2){dx[6],  dy[6]};
  c.c_run   = (f32x2){dx[7],  dy[7]};
  c.c_v2p   = (f32x2){dx[8],  dy[8]};
  c.c_vad   = (f32x2){dx[9],  dy[9]};
  c.c_phr   = (f32x2){dx[10], dy[10]};
  c.vml     = (f32x2){dx[11], dy[11]};
  c.inv_vml = (f32x2){dx[12], dy[12]};

  float w1x[LENF], w2x[LENF], w1y[LENF], w2y[LENF];
  uh_lane(ppx[12] * (20.f - 0.3f) + 0.3f, ppx[13] * (5.f - 0.01f) + 0.01f, w1x);
  uh_lane(ppx[14] * (13.f - 0.5f) + 0.5f, ppx[15] * (1.5f - 0.15f) + 0.15f, w2x);
  uh_lane(ppy[12] * (20.f - 0.3f) + 0.3f, ppy[13] * (5.f - 0.01f) + 0.01f, w1y);
  uh_lane(ppy[14] * (13.f - 0.5f) + 0.5f, ppy[15] * (1.5f - 0.15f) + 0.15f, w2y);
#pragma unroll
  for (int l = 0; l < LENF; ++l) {
    c.w1[l] = (f32x2){w1x[l], w1y[l]};
    c.w2[l] = (f32x2){w2x[l], w2y[l]};
  }

  c.sog = (f32x2){NZ, NZ}; c.wis = c.sog; c.vad = c.sog; c.phr = c.sog;
#pragma unroll
  for (int l = 0; l < LENF - 1; ++l) {
    c.s1[l] = (f32x2){0.f, 0.f};
    c.s2[l] = (f32x2){0.f, 0.f};
  }
}

// One recurrence step for both cells + two cells-packed transposed FIRs.
// Returns {out_x, out_y}.
__device__ __forceinline__ f32x2 step_pair(Pair& c, f32x2 p, f32x2 tm, f32x2 pe) {
  const f32x2 zero = {0.f, 0.f};
  const f32x2 nz   = {NZ, NZ};
  f32x2 rain;
  rain.x = (tm.x >= 0.f) ? p.x : 0.f;
  rain.y = (tm.y >= 0.f) ? p.y : 0.f;
  f32x2 snow = p - rain;
  f32x2 pf;   // Kf * (Tbf-tm)^exp_fe, per lane (v_log/v_exp are base-2)
  pf.x = c.Kf.x * __builtin_amdgcn_exp2f(
      c.exp_fe.x * __builtin_amdgcn_logf(fmaxf(c.Tbf.x - tm.x, NZ)));
  pf.y = c.Kf.y * __builtin_amdgcn_exp2f(
      c.exp_fe.y * __builtin_amdgcn_logf(fmaxf(c.Tbf.y - tm.y, NZ)));
  f32x2 freeze = vmin2(pf, c.wis);
  c.wis = c.wis - freeze;
  f32x2 sos = c.sog + freeze + snow;
  f32x2 melt = vmin2(vmax2(c.ddf * (tm - c.Tbm), zero), sos);
  c.sog = sos - melt;
  f32x2 retention = c.wrf * c.sog;
  f32x2 wtmp = c.wis + melt + rain;
  f32x2 avail = vmax2(wtmp - retention, zero);
  c.wis = vmin2(wtmp, retention);   // == avail>0 ? retention : wtmp
  f32x2 ratio = c.vad * c.inv_vml;
  f32x2 ht0 = c.c_run * ratio * avail;
  f32x2 infil = avail - ht0;
  f32x2 ht1 = c.c_v2p * ratio * c.vad;
  f32x2 ht2 = c.c_vad * c.vad;
  f32x2 ht3 = c.c_phr * c.phr;
  f32x2 aet = vmin2(c.ET_eff * pe, c.vad);
  c.vad = c.vad + infil - aet - ht1 - ht2;
  f32x2 overflow = vmax2(c.vad - c.vml, zero);
  c.vad = vmin2(vmax2(c.vad, nz), c.vml);
  ht0 = ht0 + overflow;
  c.phr = vmax2(c.phr + ht1 - ht3, nz);
  f32x2 qd = ht2 + ht3;

  f32x2 o = (c.s1[0] + c.w1[0] * ht0) + (c.s2[0] + c.w2[0] * qd);
#pragma unroll
  for (int l = 0; l < LENF - 2; ++l) {
    c.s1[l] = c.s1[l + 1] + c.w1[l + 1] * ht0;   // v_pk_fma_f32
    c.s2[l] = c.s2[l + 1] + c.w2[l + 1] * qd;
  }
  c.s1[LENF - 2] = c.w1[LENF - 1] * ht0;
  c.s2[LENF - 2] = c.w2[LENF - 1] * qd;
  return o;
}

__global__ __launch_bounds__(64, 1) void exphydro_kernel(
    const float* __restrict__ x,      // (T, G, 3)
    const float* __restrict__ params, // (G, 16)
    float* __restrict__ out,          // (T, G)
    int G, int T)
{
  const int half = (G + 1) >> 1;
  int g = blockIdx.x * 64 + threadIdx.x;
  if (g >= half) return;
  const int g2 = g + half;
  const bool hasY = (g2 < G);
  const int g2s = hasY ? g2 : (G - 1);     // safe index (store suppressed)

  Pair c;
  init_pair(c, params + (size_t)g * 16, params + (size_t)g2s * 16);

  const unsigned Gu = (unsigned)G;
  const R3* xgx = (const R3*)x + g;        // record idx = t*G + g (<2^31 B)
  const R3* xgy = (const R3*)x + g2s;
  float* ox = out + g;
  float* oy = out + g2s;

  // chunk staging, cells-packed at load time: 2 buf x 5 x 3 x f32x2 = 60 VGPR
  f32x2 PA[BLK], TA[BLK], EA[BLK], PB[BLK], TB[BLK], EB[BLK];

  const int nch = T / BLK;                 // 219 for T=1095
  const int rem = T - nch * BLK;           // 0

#define LOADC(P_, T_, E_, ch)                                         \
  {                                                                   \
    unsigned b0_ = (unsigned)(ch) * (unsigned)BLK * Gu;               \
    _Pragma("unroll")                                                 \
    for (int j = 0; j < BLK; ++j) {                                   \
      R3 rx_ = xgx[b0_ + (unsigned)j * Gu];                           \
      R3 ry_ = xgy[b0_ + (unsigned)j * Gu];                           \
      P_[j] = (f32x2){rx_.p, ry_.p};                                  \
      T_[j] = (f32x2){rx_.t, ry_.t};                                  \
      E_[j] = (f32x2){rx_.e, ry_.e};                                  \
    }                                                                 \
  }

#define STEPC(P_, T_, E_)                                             \
  {                                                                   \
    _Pragma("unroll")                                                 \
    for (int i = 0; i < BLK; ++i) {                                   \
      f32x2 o_ = step_pair(c, P_[i], T_[i], E_[i]);                   \
      *ox = o_.x;                                                     \
      if (hasY) *oy = o_.y;                                           \
      ox += G; oy += G;                                               \
    }                                                                 \
  }

  if (nch > 0) LOADC(PA, TA, EA, 0);

  int k = 0;
  while (k + 2 <= nch) {
    LOADC(PB, TB, EB, k + 1);        // prefetch next chunk
    STEPC(PA, TA, EA);
    if (k + 2 < nch) LOADC(PA, TA, EA, k + 2);
    STEPC(PB, TB, EB);
    k += 2;
  }
  if (k < nch) {                     // odd chunk count: last chunk in A
    STEPC(PA, TA, EA);
  }
  if (rem > 0) {                     // generic tail (empty at T=1095)
    unsigned b0 = (unsigned)nch * (unsigned)BLK * Gu;
    for (int j = 0; j < rem; ++j) {
      R3 rx = xgx[b0 + (unsigned)j * Gu];
      R3 ry = xgy[b0 + (unsigned)j * Gu];
      f32x2 o_ = step_pair(c, (f32x2){rx.p, ry.p}, (f32x2){rx.t, ry.t},
                           (f32x2){rx.e, ry.e});
      *ox = o_.x;
      if (hasY) *oy = o_.y;
      ox += G; oy += G;
    }
  }

#undef LOADC
#undef STEPC
}

extern "C" void kernel_launch(void* const* d_in, const int* in_sizes, int n_in,
                              void* d_out, int out_size, void* d_ws, size_t ws_size,
                              hipStream_t stream) {
  const float* x      = (const float*)d_in[0];
  const float* params = (const float*)d_in[1];
  float* out          = (float*)d_out;

  int G = in_sizes[1] / 16;               // 15000
  int T = in_sizes[0] / (G * 3);          // 1095

  int half  = (G + 1) / 2;                // 2 cells per thread, lane-packed
  int block = 64;
  int grid  = (half + block - 1) / block; // 118 waves
  exphydro_kernel<<<grid, block, 0, stream>>>(x, params, out, G, T);
}

// Round 8
// 149.506 us; speedup vs baseline: 2.7751x; 2.7751x over previous
//
#include <hip/hip_runtime.h>

#define LENF 15
#define NZ   1e-5f

typedef float f32x2 __attribute__((ext_vector_type(2)));

struct R3 { float p, t, e; };   // 12B record -> global_load_dwordx3

__global__ __launch_bounds__(64, 1) void exphydro_kernel(
    const float* __restrict__ x,      // (T, G, 3): prcp, tmean, pet
    const float* __restrict__ params, // (G, 16)
    float* __restrict__ out,          // (T, G)
    int G, int T)
{
  int g = blockIdx.x * 64 + threadIdx.x;
  if (g >= G) return;

  // ---- params (+ pre-combined constants) ----
  const float* pp = params + (size_t)g * 16;
  float P0[16];
#pragma unroll
  for (int i = 0; i < 16; ++i) P0[i] = pp[i];

  const float ddf    = P0[0]  * 40.f;
  const float Tbm    = P0[1]  * 5.f  - 2.f;
  const float wrf    = P0[2]  * 0.5f;
  const float Tbf    = P0[3]  * 7.f  - 5.f;
  const float Kf     = P0[4]  * 5.f;
  const float exp_fe = P0[5];
  const float ET_eff = P0[6];
  const float c_vad  = P0[9]  * 0.1f;
  const float c_phr  = P0[10] * (0.01f - 1e-5f) + 1e-5f;
  const float vml    = P0[11] * (500.f - 0.001f) + 0.001f;
  const float inv_vml = 1.f / vml;
  const float crp    = P0[7] * inv_vml;                         // c_run/vml
  const float cvp    = (P0[8] * (0.02f - 1e-5f) + 1e-5f) * inv_vml; // c_v2p/vml
  const float mpb    = ddf * Tbm;                               // melt bias
  const float a1     = P0[12] * (20.f - 0.3f)  + 0.3f;
  const float b1     = P0[13] * (5.f  - 0.01f) + 0.01f;
  const float a2     = P0[14] * (13.f - 0.5f)  + 0.5f;
  const float b2     = P0[15] * (1.5f - 0.15f) + 0.15f;

  // ---- gamma UH weights (lgamma/theta terms cancel under normalization) ----
  f32x2 wv[LENF];
  {
    float lw1[LENF], lw2[LENF];
    float m1 = -1e30f, m2 = -1e30f;
    const float ib1 = 1.f / b1, ib2 = 1.f / b2;
#pragma unroll
    for (int l = 0; l < LENF; ++l) {
      float tt = l + 0.5f;
      float lt = __logf(tt);
      lw1[l] = (a1 - 1.f) * lt - tt * ib1;
      lw2[l] = (a2 - 1.f) * lt - tt * ib2;
      m1 = fmaxf(m1, lw1[l]);
      m2 = fmaxf(m2, lw2[l]);
    }
    float s1 = 0.f, s2 = 0.f;
    float t1[LENF], t2[LENF];
#pragma unroll
    for (int l = 0; l < LENF; ++l) {
      t1[l] = __expf(lw1[l] - m1); s1 += t1[l];
      t2[l] = __expf(lw2[l] - m2); s2 += t2[l];
    }
    const float r1 = 1.f / s1, r2 = 1.f / s2;
#pragma unroll
    for (int l = 0; l < LENF; ++l) { wv[l].x = t1[l] * r1; wv[l].y = t2[l] * r2; }
  }

  // ---- state + transposed-FIR delay line (fixed indices, no phase) ----
  float sog = NZ, wis = NZ, vad = NZ, phr = NZ;
  f32x2 D[LENF - 1];
#pragma unroll
  for (int l = 0; l < LENF - 1; ++l) D[l] = (f32x2){0.f, 0.f};

  const unsigned Gu = (unsigned)G;
  const R3* xg = (const R3*)x + g;     // record idx = t*G + g (<2^31 bytes)
  unsigned oof = (unsigned)g;          // running output index

  R3 A[LENF], B[LENF];
  float pf[LENF], mp[LENF], rp[LENF];  // PREP: transcendentals off the chain

  const int nb   = T / LENF;
  const int tail = T - nb * LENF;

#define LOAD(BUF, blk)                                                \
  {                                                                   \
    unsigned b0_ = (unsigned)(blk) * (unsigned)LENF * Gu;             \
    _Pragma("unroll")                                                 \
    for (int j = 0; j < LENF; ++j) BUF[j] = xg[b0_ + (unsigned)j * Gu]; \
  }

  // state-independent per-input work; 15 independent chains (stall filler)
#define PREP(BUF)                                                     \
  {                                                                   \
    _Pragma("unroll")                                                 \
    for (int j = 0; j < LENF; ++j) {                                  \
      float tm_ = BUF[j].t;                                           \
      pf[j] = Kf * __builtin_amdgcn_exp2f(                            \
                  exp_fe * __builtin_amdgcn_logf(fmaxf(Tbf - tm_, NZ))); \
      mp[j] = fmaxf(ddf * tm_ - mpb, 0.f);                            \
      rp[j] = ET_eff * BUF[j].e;                                      \
    }                                                                 \
  }

#define STEP(BUF, I_)                                                 \
  {                                                                   \
    float p_ = BUF[I_].p, tm_ = BUF[I_].t;                            \
    float rain = (tm_ >= 0.f) ? p_ : 0.f;                             \
    float snow = p_ - rain;                                           \
    float freeze = fminf(pf[I_], wis);                                \
    wis -= freeze;                                                    \
    float sos = sog + freeze + snow;                                  \
    float melt = fminf(mp[I_], sos);                                  \
    sog = sos - melt;                                                 \
    float ret = wrf * sog;                                            \
    float wtmp = wis + melt + rain;                                   \
    float avail = fmaxf(wtmp - ret, 0.f);                             \
    wis = fminf(wtmp, ret);      /* == avail>0 ? ret : wtmp */        \
    float t1_ = crp * vad;                                            \
    float ht0 = t1_ * avail;                                          \
    float t2_ = cvp * vad;                                            \
    float ht1 = t2_ * vad;                                            \
    float ht2 = c_vad * vad;                                          \
    float ht3 = c_phr * phr;                                          \
    float infil = avail - ht0;                                        \
    float aet = fminf(rp[I_], vad);                                   \
    float va_ = vad + infil;                                          \
    float vb_ = aet + ht1;                                            \
    float v2_ = va_ - vb_ - ht2;                                      \
    float overflow = fmaxf(v2_ - vml, 0.f);                           \
    vad = fminf(fmaxf(v2_, NZ), vml);        /* v_med3_f32 */         \
    float qx = ht0 + overflow;                                        \
    phr = fmaxf(phr + ht1 - ht3, NZ);                                 \
    f32x2 q_; q_.x = qx; q_.y = ht2 + ht3;                            \
    f32x2 o_ = D[0] + wv[0] * q_;                                     \
    _Pragma("unroll")                                                 \
    for (int l = 0; l < LENF - 2; ++l)                                \
      D[l] = D[l + 1] + wv[l + 1] * q_;        /* v_pk_fma_f32 */     \
    D[LENF - 2] = wv[LENF - 1] * q_;                                  \
    out[oof] = o_.x + o_.y;                                           \
    oof += Gu;                                                        \
  }

#define BLOCK(BUF)                                                    \
  {                                                                   \
    PREP(BUF);                                                        \
    _Pragma("unroll")                                                 \
    for (int i = 0; i < LENF; ++i) STEP(BUF, i);                      \
  }

  if (nb > 0) LOAD(A, 0);

  int k = 0;
  while (k + 2 <= nb) {
    LOAD(B, k + 1);                 // next block's loads fly over PREP+steps
    BLOCK(A);
    if (k + 2 < nb) LOAD(A, k + 2);
    BLOCK(B);
    k += 2;
  }
  if (k < nb) {                     // nb odd: last full block already in A
    BLOCK(A);
  }
  if (tail > 0) {                   // generic guarded tail (empty at T=1095)
    unsigned b0 = (unsigned)nb * (unsigned)LENF * Gu;
    for (int j = 0; j < tail; ++j) {
      A[0] = xg[b0 + (unsigned)j * Gu];
      float tm_ = A[0].t;
      pf[0] = Kf * __builtin_amdgcn_exp2f(
                  exp_fe * __builtin_amdgcn_logf(fmaxf(Tbf - tm_, NZ)));
      mp[0] = fmaxf(ddf * tm_ - mpb, 0.f);
      rp[0] = ET_eff * A[0].e;
      STEP(A, 0);
    }
  }

#undef LOAD
#undef PREP
#undef STEP
#undef BLOCK
}

extern "C" void kernel_launch(void* const* d_in, const int* in_sizes, int n_in,
                              void* d_out, int out_size, void* d_ws, size_t ws_size,
                              hipStream_t stream) {
  const float* x      = (const float*)d_in[0];
  const float* params = (const float*)d_in[1];
  float* out          = (float*)d_out;

  int G = in_sizes[1] / 16;               // 15000
  int T = in_sizes[0] / (G * 3);          // 1095

  int block = 64;                         // 1 wave/block -> 235 SIMDs busy
  int grid  = (G + block - 1) / block;
  exphydro_kernel<<<grid, block, 0, stream>>>(x, params, out, G, T);
}